// Round 6
// baseline (88.948 us; speedup 1.0000x reference)
//
#include <hip/hip_runtime.h>

// Problem constants (from reference)
#define IN_F 4096
#define OUT_F 12288
#define BATCH 8

// Tiling: 4 phases of 1024 k; 4 chunks of 256 k per phase (64 lanes x 4)
#define CHUNK 256
#define PHASE 1024
#define NPHASES (IN_F / PHASE)      // 4
#define CPP (PHASE / CHUNK)         // 4 chunks per phase
#define ROWS_PER_WAVE 4
#define WAVES_PER_BLOCK 4
#define ROWS_PER_BLOCK (ROWS_PER_WAVE * WAVES_PER_BLOCK)  // 16
#define NBLOCKS (OUT_F / ROWS_PER_BLOCK)                  // 768

// MLP-focused: 8 barriers total (vs 32), and all 16 qweight int4 loads of a
// phase are issued up-front into registers (issue order == consume order) so
// each wave keeps ~256B of qweight in flight instead of ~64B.
__global__ __launch_bounds__(256, 3)
void w4a32_gemv(const float* __restrict__ x,
                const int* __restrict__ qw,
                const float* __restrict__ scales,
                const float* __restrict__ zeros,
                float* __restrict__ out)
{
    __shared__ float xs[BATCH][PHASE];  // 32 KB

    const int tid   = threadIdx.x;
    const int wave  = tid >> 6;
    const int lane  = tid & 63;
    const int row0  = blockIdx.x * ROWS_PER_BLOCK + wave * ROWS_PER_WAVE;
    const int klane = lane << 2;        // lane's 4-k offset within a chunk

    float acc[ROWS_PER_WAVE][BATCH];
#pragma unroll
    for (int r = 0; r < ROWS_PER_WAVE; ++r)
#pragma unroll
        for (int b = 0; b < BATCH; ++b) acc[r][b] = 0.f;

    for (int p = 0; p < NPHASES; ++p) {
        const int kp = p * PHASE;

        __syncthreads();  // protect xs from previous phase's readers
        // Stage x[0:8][kp:kp+1024] -> LDS: 2048 float4 / 256 threads = 8 each
#pragma unroll
        for (int j = 0; j < 8; ++j) {
            const int idx = tid + j * 256;       // float4 index 0..2047
            const int b   = idx >> 8;            // 256 float4 per batch row
            const int kk  = (idx & 255) << 2;
            *reinterpret_cast<float4*>(&xs[b][kk]) =
                *reinterpret_cast<const float4*>(&x[b * IN_F + kp + kk]);
        }
        __syncthreads();

        // Issue ALL qweight loads for this phase (16 int4 per lane in flight),
        // in the same (c outer, r inner) order they are consumed below.
        int4 q[CPP][ROWS_PER_WAVE];
#pragma unroll
        for (int c = 0; c < CPP; ++c)
#pragma unroll
            for (int r = 0; r < ROWS_PER_WAVE; ++r)
                q[c][r] = *reinterpret_cast<const int4*>(
                    &qw[(row0 + r) * IN_F + kp + c * CHUNK + klane]);

#pragma unroll
        for (int c = 0; c < CPP; ++c) {
            const int g = p * 8 + c * 2 + (lane >> 5);  // quant group of lane's 4 k
            float4 xr[BATCH];
#pragma unroll
            for (int b = 0; b < BATCH; ++b)
                xr[b] = *reinterpret_cast<const float4*>(&xs[b][c * CHUNK + klane]);

#pragma unroll
            for (int r = 0; r < ROWS_PER_WAVE; ++r) {
                const int n = row0 + r;
                const float s  = scales[g * OUT_F + n];   // uniform per half-wave
                const float z  = zeros [g * OUT_F + n];
                const float cc = __builtin_fmaf(s, -8.f, z);  // z - 8*s
                const int4 qq = q[c][r];
                const float w0 = __builtin_fmaf((float)qq.x, s, cc);
                const float w1 = __builtin_fmaf((float)qq.y, s, cc);
                const float w2 = __builtin_fmaf((float)qq.z, s, cc);
                const float w3 = __builtin_fmaf((float)qq.w, s, cc);
#pragma unroll
                for (int b = 0; b < BATCH; ++b) {
                    float a = acc[r][b];
                    a = __builtin_fmaf(w0, xr[b].x, a);
                    a = __builtin_fmaf(w1, xr[b].y, a);
                    a = __builtin_fmaf(w2, xr[b].z, a);
                    a = __builtin_fmaf(w3, xr[b].w, a);
                    acc[r][b] = a;
                }
            }
        }
    }

    // Final cross-lane reduction (once per row) + store
#pragma unroll
    for (int r = 0; r < ROWS_PER_WAVE; ++r) {
        const int n = row0 + r;
#pragma unroll
        for (int b = 0; b < BATCH; ++b) {
            float v = acc[r][b];
            v += __shfl_xor(v, 32);
            v += __shfl_xor(v, 16);
            v += __shfl_xor(v, 8);
            v += __shfl_xor(v, 4);
            v += __shfl_xor(v, 2);
            v += __shfl_xor(v, 1);
            if (lane == b) out[b * OUT_F + n] = v;  // lanes 0..7 store the 8 batches
        }
    }
}

extern "C" void kernel_launch(void* const* d_in, const int* in_sizes, int n_in,
                              void* d_out, int out_size, void* d_ws, size_t ws_size,
                              hipStream_t stream) {
    const float* x      = (const float*)d_in[0];
    const int*   qw     = (const int*)d_in[1];
    const float* scales = (const float*)d_in[2];
    const float* zeros  = (const float*)d_in[3];
    float* out = (float*)d_out;

    w4a32_gemv<<<NBLOCKS, 256, 0, stream>>>(x, qw, scales, zeros, out);
}

// Round 7
// 51.020 us; speedup vs baseline: 1.7434x; 1.7434x over previous
//
#include <hip/hip_runtime.h>

// Problem constants
#define IN_F 4096
#define OUT_F 12288
#define BATCH 8
#define NGROUPS 32

// Tiling: 256 blocks (1 per CU), 48 rows/block, 8 waves x 6 rows.
// x (128 KB) + scale/zero tables (12 KB) staged in LDS ONCE; single barrier.
#define CHUNK 256
#define NCHUNKS (IN_F / CHUNK)            // 16
#define ROWS_PER_WAVE 6
#define ROWS_PER_BLOCK 48
#define NBLOCKS (OUT_F / ROWS_PER_BLOCK)  // 256
#define THREADS 512

__global__ __launch_bounds__(THREADS, 2)
void w4a32_gemv(const float* __restrict__ x,
                const int* __restrict__ qw,
                const float* __restrict__ scales,
                const float* __restrict__ zeros,
                float* __restrict__ out)
{
    __shared__ float xs[BATCH][IN_F];                  // 128 KB
    __shared__ float szs[NGROUPS * ROWS_PER_BLOCK];    // 6 KB: scale s
    __shared__ float szc[NGROUPS * ROWS_PER_BLOCK];    // 6 KB: cc = z - 8*s

    const int tid   = threadIdx.x;
    const int wave  = tid >> 6;
    const int lane  = tid & 63;
    const int rowb  = blockIdx.x * ROWS_PER_BLOCK;
    const int wrow  = wave * ROWS_PER_WAVE;            // local row base
    const int klane = lane << 2;

    const int* qbase = qw + (size_t)(rowb + wrow) * IN_F + klane;

    // Issue chunk-0 qweight loads BEFORE staging: latency hides under staging.
    int4 qA[ROWS_PER_WAVE], qB[ROWS_PER_WAVE];
#pragma unroll
    for (int r = 0; r < ROWS_PER_WAVE; ++r)
        qA[r] = *reinterpret_cast<const int4*>(qbase + r * IN_F);

    // Stage all of x: 8192 float4 / 512 threads = 16 each, coalesced.
#pragma unroll
    for (int j = 0; j < 16; ++j) {
        const int idx = tid + j * THREADS;             // 0..8191
        const int b   = idx >> 10;                     // 1024 float4 per batch row
        const int kk  = (idx & 1023) << 2;
        *reinterpret_cast<float4*>(&xs[b][kk]) =
            *reinterpret_cast<const float4*>(&x[b * IN_F + kk]);
    }
    // Stage scales and cc = zeros - 8*scales for this block's 48 rows.
#pragma unroll
    for (int j = 0; j < 4; ++j) {
        const int idx = tid + j * THREADS;             // 0..2047
        const int g   = idx >> 6;
        const int r   = idx & 63;
        if (r < ROWS_PER_BLOCK) {
            const float s = scales[g * OUT_F + rowb + r];
            const float z = zeros [g * OUT_F + rowb + r];
            szs[g * ROWS_PER_BLOCK + r] = s;
            szc[g * ROWS_PER_BLOCK + r] = __builtin_fmaf(s, -8.f, z);
        }
    }
    __syncthreads();  // the ONLY barrier

    float acc[ROWS_PER_WAVE][BATCH];
#pragma unroll
    for (int r = 0; r < ROWS_PER_WAVE; ++r)
#pragma unroll
        for (int b = 0; b < BATCH; ++b) acc[r][b] = 0.f;

    // Consume one 256-k chunk from a named q buffer (fully unrolled).
    auto consume = [&](const int4 (&q)[ROWS_PER_WAVE], const int k0c) {
        const int g = (k0c >> 7) + (lane >> 5);        // quant group of lane's 4 k
        float4 xr[BATCH];
#pragma unroll
        for (int b = 0; b < BATCH; ++b)
            xr[b] = *reinterpret_cast<const float4*>(&xs[b][k0c + klane]);
#pragma unroll
        for (int r = 0; r < ROWS_PER_WAVE; ++r) {
            const float s  = szs[g * ROWS_PER_BLOCK + wrow + r];  // LDS broadcast
            const float cc = szc[g * ROWS_PER_BLOCK + wrow + r];
            const float w0 = __builtin_fmaf((float)q[r].x, s, cc);
            const float w1 = __builtin_fmaf((float)q[r].y, s, cc);
            const float w2 = __builtin_fmaf((float)q[r].z, s, cc);
            const float w3 = __builtin_fmaf((float)q[r].w, s, cc);
#pragma unroll
            for (int b = 0; b < BATCH; ++b) {
                float a = acc[r][b];
                a = __builtin_fmaf(w0, xr[b].x, a);
                a = __builtin_fmaf(w1, xr[b].y, a);
                a = __builtin_fmaf(w2, xr[b].z, a);
                a = __builtin_fmaf(w3, xr[b].w, a);
                acc[r][b] = a;
            }
        }
    };

    // 2-chunk software pipeline, named buffers only (no runtime indexing).
    for (int c = 0; c < NCHUNKS; c += 2) {
        const int k0 = c * CHUNK;
#pragma unroll
        for (int r = 0; r < ROWS_PER_WAVE; ++r)        // prefetch chunk c+1
            qB[r] = *reinterpret_cast<const int4*>(qbase + r * IN_F + k0 + CHUNK);

        consume(qA, k0);

        if (c + 2 < NCHUNKS) {                          // prefetch chunk c+2
#pragma unroll
            for (int r = 0; r < ROWS_PER_WAVE; ++r)
                qA[r] = *reinterpret_cast<const int4*>(qbase + r * IN_F + k0 + 2 * CHUNK);
        }

        consume(qB, k0 + CHUNK);
    }

    // Cross-lane reduction + store (lanes 0..7 hold the 8 batches)
#pragma unroll
    for (int r = 0; r < ROWS_PER_WAVE; ++r) {
        const int n = rowb + wrow + r;
#pragma unroll
        for (int b = 0; b < BATCH; ++b) {
            float v = acc[r][b];
            v += __shfl_xor(v, 32);
            v += __shfl_xor(v, 16);
            v += __shfl_xor(v, 8);
            v += __shfl_xor(v, 4);
            v += __shfl_xor(v, 2);
            v += __shfl_xor(v, 1);
            if (lane == b) out[b * OUT_F + n] = v;
        }
    }
}

extern "C" void kernel_launch(void* const* d_in, const int* in_sizes, int n_in,
                              void* d_out, int out_size, void* d_ws, size_t ws_size,
                              hipStream_t stream) {
    const float* x      = (const float*)d_in[0];
    const int*   qw     = (const int*)d_in[1];
    const float* scales = (const float*)d_in[2];
    const float* zeros  = (const float*)d_in[3];
    float* out = (float*)d_out;

    w4a32_gemv<<<NBLOCKS, THREADS, 0, stream>>>(x, qw, scales, zeros, out);
}